// Round 8
// baseline (246.511 us; speedup 1.0000x reference)
//
#include <hip/hip_runtime.h>

#define BB 4096
#define TT 512
#define HH 32

typedef _Float16 half8 __attribute__((ext_vector_type(8)));  // MFMA A/B frag (4 VGPRs)
typedef _Float16 h2    __attribute__((ext_vector_type(2)));  // packed f16 pair
typedef float    f32x4 __attribute__((ext_vector_type(4)));  // MFMA C/D

#define MFMA16F(a, b, c) __builtin_amdgcn_mfma_f32_16x16x32_f16((a), (b), (c), 0, 0, 0)

union frag_u { half8 h8; h2 p[4]; };

// v_cvt_pkrtz_f16_f32 returns a __fp16 ext-vector; bit-cast to _Float16 vector.
__device__ __forceinline__ h2 pkrtz(float a, float b) {
    auto r = __builtin_amdgcn_cvt_pkrtz(a, b);
    union { decltype(r) i; h2 o; } u;
    u.i = r;
    return u.o;
}

// tanh(v) ~= v * P(v^2), quintic P, Chebyshev fit on |v|<=2.75 (max err ~2e-3).
// Estrin evaluation: dependency depth ~8 (vs 10 Horner) -- we are chain-bound.
__device__ __forceinline__ h2 tanh_h2(h2 v) {
    const h2 LO = {(_Float16)(-2.75f), (_Float16)(-2.75f)};
    const h2 HI = {(_Float16)(2.75f), (_Float16)(2.75f)};
    const h2 C0 = {(_Float16)(0.9976293f), (_Float16)(0.9976293f)};
    const h2 C1 = {(_Float16)(-0.3098016f), (_Float16)(-0.3098016f)};
    const h2 C2 = {(_Float16)(0.0889744f), (_Float16)(0.0889744f)};
    const h2 C3 = {(_Float16)(-0.0163448f), (_Float16)(-0.0163448f)};
    const h2 C4 = {(_Float16)(0.0016113f), (_Float16)(0.0016113f)};
    const h2 C5 = {(_Float16)(-0.00006405f), (_Float16)(-0.00006405f)};
    v = __builtin_elementwise_min(v, HI);
    v = __builtin_elementwise_max(v, LO);
    h2 u = v * v;                                   // depth +1
    h2 w = u * u;                                   // +1
    h2 p01 = __builtin_elementwise_fma(u, C1, C0);  // parallel with w
    h2 p23 = __builtin_elementwise_fma(u, C3, C2);
    h2 p45 = __builtin_elementwise_fma(u, C5, C4);
    h2 q = __builtin_elementwise_fma(w, p45, p23);  // +1 after w
    h2 t = __builtin_elementwise_fma(w, q, p01);    // +1
    return v * t;                                   // +1
}

// D = W @ H^T per step, M = h'-rows (2 tiles of 16), N = 16 batches.
// Row permutation pi_t(m) = 8*(m>>2) + (m&3) + 4t makes the C/D output layout
// equal the B-operand layout of the next matvec -> recurrence stays in registers.
//
// Round-8 change: layer-1 pre-activation = (Wih1.h0 + b1) [MFMA, C=bias] plus
// (Whh1.h1 + 0) [MFMA, C=0], combined by 8 v_add_f32. This removes the
// dbp->d10 MFMA->MFMA C-operand serialization from the h1 recurrence:
// both recurrences are now 1 MFMA stage + tanh per step (chain-bound regime;
// rounds 5/7 showed issue-side changes are neutral).
__global__ __launch_bounds__(64) void rnn2_mfma(
    const float* __restrict__ x,      // [B, T]
    const float* __restrict__ hstate, // [2, B, H]
    const float* __restrict__ Wih0,   // [H, 1]
    const float* __restrict__ Whh0,   // [H, H]
    const float* __restrict__ bih0,   // [H]
    const float* __restrict__ bhh0,   // [H]
    const float* __restrict__ Wih1,   // [H, H]
    const float* __restrict__ Whh1,   // [H, H]
    const float* __restrict__ bih1,   // [H]
    const float* __restrict__ bhh1,   // [H]
    const float* __restrict__ Wfc,    // [1, H]
    const float* __restrict__ bfc,    // [1]
    float* __restrict__ out)          // [B] pred ++ [2,B,H] h_new
{
    const int l = threadIdx.x;   // 0..63
    const int q = l >> 4;        // lane quad -> k-offset 8q
    const int n = l & 15;        // batch-in-tile / matrix row m
    const int b = blockIdx.x * 16 + n;

    // ---- weight A-fragments (f16), permuted rows ----
    const int r0 = 8 * (n >> 2) + (n & 3);
    half8 A0[2], A1i[2], A1h[2];
#pragma unroll
    for (int t = 0; t < 2; ++t) {
        const int row = r0 + 4 * t;
        const float* p0 = Whh0 + row * HH + q * 8;
        const float* p1 = Wih1 + row * HH + q * 8;
        const float* p2 = Whh1 + row * HH + q * 8;
        frag_u f0, f1, f2;
#pragma unroll
        for (int jj = 0; jj < 4; ++jj) {
            f0.p[jj] = h2{(_Float16)p0[2 * jj], (_Float16)p0[2 * jj + 1]};
            f1.p[jj] = h2{(_Float16)p1[2 * jj], (_Float16)p1[2 * jj + 1]};
            f2.p[jj] = h2{(_Float16)p2[2 * jj], (_Float16)p2[2 * jj + 1]};
        }
        A0[t] = f0.h8; A1i[t] = f1.h8; A1h[t] = f2.h8;
    }

    // ---- per-lane constants over j=0..7 (h' = 8q + j) ----
    float wxs[8], b0s[8], wfc8[8];
#pragma unroll
    for (int j = 0; j < 8; ++j) {
        const int hh = 8 * q + j;
        wxs[j]  = Wih0[hh];
        b0s[j]  = bih0[hh] + bhh0[hh];
        wfc8[j] = Wfc[hh];
    }
    f32x4 c1t0, c1t1;   // layer-1 bias as C of the Wih1 MFMA
#pragma unroll
    for (int r = 0; r < 4; ++r) {
        c1t0[r] = bih1[8 * q + r] + bhh1[8 * q + r];
        c1t1[r] = bih1[8 * q + 4 + r] + bhh1[8 * q + 4 + r];
    }
    const f32x4 zz = {0.f, 0.f, 0.f, 0.f};

    // ---- initial h state as f16 B-fragments ----
    frag_u hb0, hb1;
    {
        const float* p0 = hstate + b * HH + 8 * q;
        const float* p1 = hstate + BB * HH + b * HH + 8 * q;
#pragma unroll
        for (int jj = 0; jj < 4; ++jj) {
            hb0.p[jj] = h2{(_Float16)p0[2 * jj], (_Float16)p0[2 * jj + 1]};
            hb1.p[jj] = h2{(_Float16)p1[2 * jj], (_Float16)p1[2 * jj + 1]};
        }
    }

    f32x4 dbp0, dbp1;   // Whh1 . h1(s-2)  (no bias; bias rides in d10's C)

    const float4* xp = (const float4*)(x + (size_t)b * TT);
    float4 xc = xp[0];

    // ---- prologue: h0(0) from h0(-1); dbp from h1(-1) ----
    {
        f32x4 c00, c01;
#pragma unroll
        for (int r = 0; r < 4; ++r) {
            c00[r] = fmaf(wxs[r], xc.x, b0s[r]);
            c01[r] = fmaf(wxs[4 + r], xc.x, b0s[4 + r]);
        }
        f32x4 d00 = MFMA16F(A0[0], hb0.h8, c00);
        f32x4 d01 = MFMA16F(A0[1], hb0.h8, c01);
        dbp0 = MFMA16F(A1h[0], hb1.h8, zz);
        dbp1 = MFMA16F(A1h[1], hb1.h8, zz);
        hb0.p[0] = tanh_h2(pkrtz(d00[0], d00[1]));
        hb0.p[1] = tanh_h2(pkrtz(d00[2], d00[3]));
        hb0.p[2] = tanh_h2(pkrtz(d01[0], d01[1]));
        hb0.p[3] = tanh_h2(pkrtz(d01[2], d01[3]));
    }

    // STEP for step s: enter with hb0 = h0(s-1), dbp = Whh1.h1(s-2).
    // Computes h1(s-1) (via d10+dbp add) and h0(s); refills dbp from h1(s-1).
#define STEP(XT)                                                              \
    {                                                                         \
        f32x4 d10 = MFMA16F(A1i[0], hb0.h8, c1t0);   /* Wih1.h0(s-1)+b1 */    \
        f32x4 d11 = MFMA16F(A1i[1], hb0.h8, c1t1);                            \
        f32x4 c00, c01;                                                       \
        _Pragma("unroll")                                                     \
        for (int r = 0; r < 4; ++r) {                                         \
            c00[r] = fmaf(wxs[r], (XT), b0s[r]);                              \
            c01[r] = fmaf(wxs[4 + r], (XT), b0s[4 + r]);                      \
        }                                                                     \
        f32x4 d00 = MFMA16F(A0[0], hb0.h8, c00);                              \
        f32x4 d01 = MFMA16F(A0[1], hb0.h8, c01);                              \
        f32x4 va = d10 + dbp0;        /* 8 v_add_f32: break MFMA->MFMA C */   \
        f32x4 vb = d11 + dbp1;                                                \
        hb1.p[0] = tanh_h2(pkrtz(va[0], va[1]));                              \
        hb1.p[1] = tanh_h2(pkrtz(va[2], va[3]));                              \
        hb1.p[2] = tanh_h2(pkrtz(vb[0], vb[1]));                              \
        hb1.p[3] = tanh_h2(pkrtz(vb[2], vb[3]));                              \
        dbp0 = MFMA16F(A1h[0], hb1.h8, zz);                                   \
        dbp1 = MFMA16F(A1h[1], hb1.h8, zz);                                   \
        hb0.p[0] = tanh_h2(pkrtz(d00[0], d00[1]));                            \
        hb0.p[1] = tanh_h2(pkrtz(d00[2], d00[3]));                            \
        hb0.p[2] = tanh_h2(pkrtz(d01[0], d01[1]));                            \
        hb0.p[3] = tanh_h2(pkrtz(d01[2], d01[3]));                            \
    }

    // steps s = 1..3
    STEP(xc.y);
    STEP(xc.z);
    STEP(xc.w);
    // steps s = 4k..4k+3 for k = 1..127, with one-iteration x prefetch
    xc = xp[1];
    for (int k = 1; k < TT / 4 - 1; ++k) {
        float4 xn = xp[k + 1];
        STEP(xc.x);
        STEP(xc.y);
        STEP(xc.z);
        STEP(xc.w);
        xc = xn;
    }
    STEP(xc.x);
    STEP(xc.y);
    STEP(xc.z);
    STEP(xc.w);

    // tail: h1(511) = tanh(Wih1.h0(511) + b1 + dbp)
    {
        f32x4 d10 = MFMA16F(A1i[0], hb0.h8, c1t0);
        f32x4 d11 = MFMA16F(A1i[1], hb0.h8, c1t1);
        f32x4 va = d10 + dbp0;
        f32x4 vb = d11 + dbp1;
        hb1.p[0] = tanh_h2(pkrtz(va[0], va[1]));
        hb1.p[1] = tanh_h2(pkrtz(va[2], va[3]));
        hb1.p[2] = tanh_h2(pkrtz(vb[0], vb[1]));
        hb1.p[3] = tanh_h2(pkrtz(vb[2], vb[3]));
    }

    // ---- epilogue ----
    float hf0[8], hf1[8];
#pragma unroll
    for (int jj = 0; jj < 4; ++jj) {
        hf0[2 * jj]     = (float)hb0.p[jj].x;
        hf0[2 * jj + 1] = (float)hb0.p[jj].y;
        hf1[2 * jj]     = (float)hb1.p[jj].x;
        hf1[2 * jj + 1] = (float)hb1.p[jj].y;
    }
    float p = 0.f;
#pragma unroll
    for (int j = 0; j < 8; ++j) p = fmaf(wfc8[j], hf1[j], p);
    p += __shfl_xor(p, 16);
    p += __shfl_xor(p, 32);
    if (q == 0) out[b] = p + bfc[0];

#pragma unroll
    for (int j = 0; j < 8; ++j) {
        out[BB + b * HH + 8 * q + j]           = hf0[j];
        out[BB + BB * HH + b * HH + 8 * q + j] = hf1[j];
    }
}

extern "C" void kernel_launch(void* const* d_in, const int* in_sizes, int n_in,
                              void* d_out, int out_size, void* d_ws, size_t ws_size,
                              hipStream_t stream) {
    const float* x      = (const float*)d_in[0];
    const float* hstate = (const float*)d_in[1];
    const float* Wih0   = (const float*)d_in[2];
    const float* Whh0   = (const float*)d_in[3];
    const float* bih0   = (const float*)d_in[4];
    const float* bhh0   = (const float*)d_in[5];
    const float* Wih1   = (const float*)d_in[6];
    const float* Whh1   = (const float*)d_in[7];
    const float* bih1   = (const float*)d_in[8];
    const float* bhh1   = (const float*)d_in[9];
    const float* Wfc    = (const float*)d_in[10];
    const float* bfc    = (const float*)d_in[11];
    float* out = (float*)d_out;

    dim3 grid(BB / 16);  // 256 blocks x 1 wave, one 16-batch tile each
    dim3 block(64);
    hipLaunchKernelGGL(rnn2_mfma, grid, block, 0, stream,
                       x, hstate, Wih0, Whh0, bih0, bhh0,
                       Wih1, Whh1, bih1, bhh1, Wfc, bfc, out);
}

// Round 10
// 245.273 us; speedup vs baseline: 1.0050x; 1.0050x over previous
//
#include <hip/hip_runtime.h>

#define BB 4096
#define TT 512
#define HH 32

typedef _Float16 half8 __attribute__((ext_vector_type(8)));  // MFMA A/B frag (4 VGPRs)
typedef _Float16 h2    __attribute__((ext_vector_type(2)));  // packed f16 pair
typedef float    f32x4 __attribute__((ext_vector_type(4)));  // MFMA C/D

#define MFMA16F(a, b, c) __builtin_amdgcn_mfma_f32_16x16x32_f16((a), (b), (c), 0, 0, 0)

union frag_u { half8 h8; h2 p[4]; };

// v_cvt_pkrtz_f16_f32 returns a __fp16 ext-vector; bit-cast to _Float16 vector.
__device__ __forceinline__ h2 pkrtz(float a, float b) {
    auto r = __builtin_amdgcn_cvt_pkrtz(a, b);
    union { decltype(r) i; h2 o; } u;
    u.i = r;
    return u.o;
}

// tanh(v) ~= v * P(v^2), quintic P, Chebyshev fit on |v|<=2.75 (max err ~2e-3).
// Evaluated in fp32 directly on MFMA f32 outputs: 1 med3 (clamp) + 1 mul +
// 5 fma + 1 mul = 8 full-rate f32 ops/value. Replaces the f16 path whose
// exec-cycle count (r7 PMC: ~440 VALU cyc/step) exceeded the packed-op model.
__device__ __forceinline__ float tanh_f32(float v) {
    v = __builtin_amdgcn_fmed3f(v, -2.75f, 2.75f);
    float u = v * v;
    float t = fmaf(u, -0.00006405f, 0.0016113f);
    t = fmaf(u, t, -0.0163448f);
    t = fmaf(u, t, 0.0889744f);
    t = fmaf(u, t, -0.3098016f);
    t = fmaf(u, t, 0.9976293f);
    return v * t;
}

// D = W @ H^T per step, M = h'-rows (2 tiles of 16), N = 16 batches.
// Row permutation pi_t(m) = 8*(m>>2) + (m&3) + 4t makes the C/D output layout
// equal the B-operand layout of the next matvec -> recurrence stays in registers.
// Structure = round 7 (known good: passed, stable, 159us). Only the activation
// path changed (f32 eval + pack-after instead of pack-before + f16 poly):
// regime is VALU-execution-occupancy bound (r4: 4 independent chains -> 4.3x
// time; r5/r8 reorderings neutral/negative), so cut exec cycles.
__global__ __launch_bounds__(64) void rnn2_mfma(
    const float* __restrict__ x,      // [B, T]
    const float* __restrict__ hstate, // [2, B, H]
    const float* __restrict__ Wih0,   // [H, 1]
    const float* __restrict__ Whh0,   // [H, H]
    const float* __restrict__ bih0,   // [H]
    const float* __restrict__ bhh0,   // [H]
    const float* __restrict__ Wih1,   // [H, H]
    const float* __restrict__ Whh1,   // [H, H]
    const float* __restrict__ bih1,   // [H]
    const float* __restrict__ bhh1,   // [H]
    const float* __restrict__ Wfc,    // [1, H]
    const float* __restrict__ bfc,    // [1]
    float* __restrict__ out)          // [B] pred ++ [2,B,H] h_new
{
    const int l = threadIdx.x;   // 0..63
    const int q = l >> 4;        // lane quad -> k-offset 8q
    const int n = l & 15;        // batch-in-tile / matrix row m
    const int b = blockIdx.x * 16 + n;

    // ---- weight A-fragments (f16), permuted rows ----
    const int r0 = 8 * (n >> 2) + (n & 3);
    half8 A0[2], A1i[2], A1h[2];
#pragma unroll
    for (int t = 0; t < 2; ++t) {
        const int row = r0 + 4 * t;
        const float* p0 = Whh0 + row * HH + q * 8;
        const float* p1 = Wih1 + row * HH + q * 8;
        const float* p2 = Whh1 + row * HH + q * 8;
        frag_u f0, f1, f2;
#pragma unroll
        for (int jj = 0; jj < 4; ++jj) {
            f0.p[jj] = h2{(_Float16)p0[2 * jj], (_Float16)p0[2 * jj + 1]};
            f1.p[jj] = h2{(_Float16)p1[2 * jj], (_Float16)p1[2 * jj + 1]};
            f2.p[jj] = h2{(_Float16)p2[2 * jj], (_Float16)p2[2 * jj + 1]};
        }
        A0[t] = f0.h8; A1i[t] = f1.h8; A1h[t] = f2.h8;
    }

    // ---- per-lane constants over j=0..7 (h' = 8q + j) ----
    float wxs[8], b0s[8], wfc8[8];
#pragma unroll
    for (int j = 0; j < 8; ++j) {
        const int hh = 8 * q + j;
        wxs[j]  = Wih0[hh];
        b0s[j]  = bih0[hh] + bhh0[hh];
        wfc8[j] = Wfc[hh];
    }
    f32x4 c1t0, c1t1;   // layer-1 bias, rides as C of the Whh1 MFMA (r7 chaining)
#pragma unroll
    for (int r = 0; r < 4; ++r) {
        c1t0[r] = bih1[8 * q + r] + bhh1[8 * q + r];
        c1t1[r] = bih1[8 * q + 4 + r] + bhh1[8 * q + 4 + r];
    }

    // ---- initial h state as f16 B-fragments ----
    frag_u hb0, hb1;
    {
        const float* p0 = hstate + b * HH + 8 * q;
        const float* p1 = hstate + BB * HH + b * HH + 8 * q;
#pragma unroll
        for (int jj = 0; jj < 4; ++jj) {
            hb0.p[jj] = h2{(_Float16)p0[2 * jj], (_Float16)p0[2 * jj + 1]};
            hb1.p[jj] = h2{(_Float16)p1[2 * jj], (_Float16)p1[2 * jj + 1]};
        }
    }

    float hf0[8], hf1[8];   // f32 tanh outputs (live-out for epilogue)
    f32x4 dbp0, dbp1;       // pending bias1 + Whh1 . h1(s-2)

    const float4* xp = (const float4*)(x + (size_t)b * TT);
    float4 xc = xp[0];

    // ---- prologue: layer-0 step 0, and pending db for layer-1 step 0 ----
    {
        f32x4 c00, c01;
#pragma unroll
        for (int r = 0; r < 4; ++r) {
            c00[r] = fmaf(wxs[r], xc.x, b0s[r]);
            c01[r] = fmaf(wxs[4 + r], xc.x, b0s[4 + r]);
        }
        f32x4 d00 = MFMA16F(A0[0], hb0.h8, c00);
        f32x4 d01 = MFMA16F(A0[1], hb0.h8, c01);
        dbp0 = MFMA16F(A1h[0], hb1.h8, c1t0);
        dbp1 = MFMA16F(A1h[1], hb1.h8, c1t1);
#pragma unroll
        for (int r = 0; r < 4; ++r) {
            hf0[r]     = tanh_f32(d00[r]);
            hf0[4 + r] = tanh_f32(d01[r]);
        }
#pragma unroll
        for (int jj = 0; jj < 4; ++jj)
            hb0.p[jj] = pkrtz(hf0[2 * jj], hf0[2 * jj + 1]);
    }

    // STEP: enter with hb0=h0(s-1), hb1=h1(s-2), dbp=b1+Whh1.h1(s-2).
    // Computes h1(s-1) and h0(s); refills dbp with b1+Whh1.h1(s-1).
#define STEP(XT)                                                              \
    {                                                                         \
        f32x4 d10 = MFMA16F(A1i[0], hb0.h8, dbp0);                            \
        f32x4 d11 = MFMA16F(A1i[1], hb0.h8, dbp1);                            \
        f32x4 c00, c01;                                                       \
        _Pragma("unroll")                                                     \
        for (int r = 0; r < 4; ++r) {                                         \
            c00[r] = fmaf(wxs[r], (XT), b0s[r]);                              \
            c01[r] = fmaf(wxs[4 + r], (XT), b0s[4 + r]);                      \
        }                                                                     \
        f32x4 d00 = MFMA16F(A0[0], hb0.h8, c00);                              \
        f32x4 d01 = MFMA16F(A0[1], hb0.h8, c01);                              \
        _Pragma("unroll")                                                     \
        for (int r = 0; r < 4; ++r) {                                         \
            hf1[r]     = tanh_f32(d10[r]);                                    \
            hf1[4 + r] = tanh_f32(d11[r]);                                    \
        }                                                                     \
        _Pragma("unroll")                                                     \
        for (int jj = 0; jj < 4; ++jj)                                        \
            hb1.p[jj] = pkrtz(hf1[2 * jj], hf1[2 * jj + 1]);                  \
        dbp0 = MFMA16F(A1h[0], hb1.h8, c1t0);                                 \
        dbp1 = MFMA16F(A1h[1], hb1.h8, c1t1);                                 \
        _Pragma("unroll")                                                     \
        for (int r = 0; r < 4; ++r) {                                         \
            hf0[r]     = tanh_f32(d00[r]);                                    \
            hf0[4 + r] = tanh_f32(d01[r]);                                    \
        }                                                                     \
        _Pragma("unroll")                                                     \
        for (int jj = 0; jj < 4; ++jj)                                        \
            hb0.p[jj] = pkrtz(hf0[2 * jj], hf0[2 * jj + 1]);                  \
    }

    // main loop: k = 0..126 handles s = 4k+1 .. 4k+4
    for (int k = 0; k < TT / 4 - 1; ++k) {
        float4 xn = xp[k + 1];
        STEP(xc.y);
        STEP(xc.z);
        STEP(xc.w);
        STEP(xn.x);
        xc = xn;
    }
    // s = 509, 510, 511
    STEP(xc.y);
    STEP(xc.z);
    STEP(xc.w);

    // tail: layer-1 step 511
    {
        f32x4 d10 = MFMA16F(A1i[0], hb0.h8, dbp0);
        f32x4 d11 = MFMA16F(A1i[1], hb0.h8, dbp1);
#pragma unroll
        for (int r = 0; r < 4; ++r) {
            hf1[r]     = tanh_f32(d10[r]);
            hf1[4 + r] = tanh_f32(d11[r]);
        }
    }

    // ---- epilogue ----
    float p = 0.f;
#pragma unroll
    for (int j = 0; j < 8; ++j) p = fmaf(wfc8[j], hf1[j], p);
    p += __shfl_xor(p, 16);
    p += __shfl_xor(p, 32);
    if (q == 0) out[b] = p + bfc[0];

#pragma unroll
    for (int j = 0; j < 8; ++j) {
        out[BB + b * HH + 8 * q + j]           = hf0[j];
        out[BB + BB * HH + b * HH + 8 * q + j] = hf1[j];
    }
}

extern "C" void kernel_launch(void* const* d_in, const int* in_sizes, int n_in,
                              void* d_out, int out_size, void* d_ws, size_t ws_size,
                              hipStream_t stream) {
    const float* x      = (const float*)d_in[0];
    const float* hstate = (const float*)d_in[1];
    const float* Wih0   = (const float*)d_in[2];
    const float* Whh0   = (const float*)d_in[3];
    const float* bih0   = (const float*)d_in[4];
    const float* bhh0   = (const float*)d_in[5];
    const float* Wih1   = (const float*)d_in[6];
    const float* Whh1   = (const float*)d_in[7];
    const float* bih1   = (const float*)d_in[8];
    const float* bhh1   = (const float*)d_in[9];
    const float* Wfc    = (const float*)d_in[10];
    const float* bfc    = (const float*)d_in[11];
    float* out = (float*)d_out;

    dim3 grid(BB / 16);  // 256 blocks x 1 wave, one 16-batch tile each
    dim3 block(64);
    hipLaunchKernelGGL(rnn2_mfma, grid, block, 0, stream,
                       x, hstate, Wih0, Whh0, bih0, bhh0,
                       Wih1, Whh1, bih1, bhh1, Wfc, bfc, out);
}